// Round 6
// baseline (568.067 us; speedup 1.0000x reference)
//
#include <hip/hip_runtime.h>

// MultiHeadedAttention: B=4 S=2048 D=1024 H=16 DK=64, fp32 in/out.
// cvt->bf16 (fused); Q/K/V proj (128x128 MFMA GEMM, global_load_lds, swizzled LDS);
// inverted bit-packed mask; barrier-free St-layout flash attention (direct global
// K/V fragment loads, mask-as-acc-init, l-via-MFMA); out proj GEMM.

#define B_ 4
#define S_ 2048
#define D_ 1024
#define H_ 16
#define DK_ 64
#define M_ (B_ * S_) // 8192

typedef __attribute__((ext_vector_type(4))) float f32x4;
typedef __attribute__((ext_vector_type(8))) short s16x8;
typedef __attribute__((ext_vector_type(8))) unsigned short u16x8;
typedef __attribute__((ext_vector_type(4))) unsigned short u16x4;

__device__ __forceinline__ unsigned short f2bf(float f) {
    union { float f; unsigned int u; } v; v.f = f;
    unsigned int u = v.u;
    return (unsigned short)((u + 0x7FFFu + ((u >> 16) & 1u)) >> 16); // RNE
}

__device__ __forceinline__ void gl2lds16(const unsigned short* g, unsigned short* l) {
    __builtin_amdgcn_global_load_lds((const __attribute__((address_space(1))) void*)g,
                                     (__attribute__((address_space(3))) void*)l, 16, 0, 0);
}

__device__ __forceinline__ void cvt_body(const float* __restrict__ x,
                                         unsigned short* __restrict__ y, int n) {
    int i = (blockIdx.x * 256 + threadIdx.x) * 8;
    if (i + 8 <= n) {
        float4 a = *(const float4*)(x + i);
        float4 b = *(const float4*)(x + i + 4);
        u16x8 r;
        r[0] = f2bf(a.x); r[1] = f2bf(a.y); r[2] = f2bf(a.z); r[3] = f2bf(a.w);
        r[4] = f2bf(b.x); r[5] = f2bf(b.y); r[6] = f2bf(b.z); r[7] = f2bf(b.w);
        *(u16x8*)(y + i) = r;
    }
}

// fused token converts (q,k,v)
__global__ __launch_bounds__(256) void cvt_bf16x3(const float* __restrict__ x0, const float* __restrict__ x1,
                                                  const float* __restrict__ x2, unsigned short* __restrict__ y0,
                                                  unsigned short* __restrict__ y1, unsigned short* __restrict__ y2,
                                                  int n) {
    const float* x = blockIdx.y == 0 ? x0 : (blockIdx.y == 1 ? x1 : x2);
    unsigned short* y = blockIdx.y == 0 ? y0 : (blockIdx.y == 1 ? y1 : y2);
    cvt_body(x, y, n);
}

// fused weight converts (wq,wk,wv,wo)
__global__ __launch_bounds__(256) void cvt_bf16x4(const float* __restrict__ x0, const float* __restrict__ x1,
                                                  const float* __restrict__ x2, const float* __restrict__ x3,
                                                  unsigned short* __restrict__ y0, unsigned short* __restrict__ y1,
                                                  unsigned short* __restrict__ y2, unsigned short* __restrict__ y3,
                                                  int n) {
    const float* x = blockIdx.y == 0 ? x0 : (blockIdx.y == 1 ? x1 : (blockIdx.y == 2 ? x2 : x3));
    unsigned short* y = blockIdx.y == 0 ? y0 : (blockIdx.y == 1 ? y1 : (blockIdx.y == 2 ? y2 : y3));
    cvt_body(x, y, n);
}

// ---------------- mask int32 -> INVERTED bitmask (1 = masked-out) ----------------
__global__ __launch_bounds__(256) void pack_mask(const int* __restrict__ m,
                                                 unsigned long long* __restrict__ pm) {
    int t = blockIdx.x * 256 + threadIdx.x;
    unsigned long long bits = __ballot(m[t] == 0);
    if ((threadIdx.x & 63) == 0) pm[t >> 6] = bits;
}

// ---------------- GEMM: Y[m][n] = (sum_k A[m][k]*Bt[n][k] + bias[n]) * scale --------
// 128x128 tile, BK=64, global_load_lds, XOR-swizzled LDS (conflict-free frag reads).
// MODE 1: bf16 -> (B,H,S,DK); MODE 2: bf16 -> (B,H,DK,S); MODE 3: fp32 M x 1024.
template <int MODE>
__global__ __launch_bounds__(256) void gemm_bt(const unsigned short* __restrict__ A,
                                               const unsigned short* __restrict__ Bt,
                                               const float* __restrict__ bias,
                                               float scale, void* __restrict__ Y) {
    __shared__ __align__(16) unsigned short As[128 * 64];
    __shared__ __align__(16) unsigned short Bs[128 * 64];
    const int tid = threadIdx.x;
    const int wave = tid >> 6, lane = tid & 63, quad = lane >> 4, l16 = lane & 15;
    const int m0 = blockIdx.x * 128, n0 = blockIdx.y * 128;
    const int rw = (wave & 1) * 64, cw = (wave >> 1) * 64;
    const int sw = l16 & 7;

    const int srow = tid >> 3, scol = ((tid & 7) ^ (srow & 7)) * 8;
    const unsigned short* ga = A + (size_t)(m0 + srow) * 1024 + scol;
    const unsigned short* gb = Bt + (size_t)(n0 + srow) * 1024 + scol;

    f32x4 acc[4][4];
#pragma unroll
    for (int mi = 0; mi < 4; mi++)
#pragma unroll
        for (int ni = 0; ni < 4; ni++) acc[mi][ni] = (f32x4){0.f, 0.f, 0.f, 0.f};

    for (int k0 = 0; k0 < 1024; k0 += 64) {
#pragma unroll
        for (int r = 0; r < 4; r++) {
            gl2lds16(ga + (size_t)(r * 32) * 1024 + k0, &As[(r * 256 + tid) * 8]);
            gl2lds16(gb + (size_t)(r * 32) * 1024 + k0, &Bs[(r * 256 + tid) * 8]);
        }
        __syncthreads();
#pragma unroll
        for (int kki = 0; kki < 2; kki++) {
            const int xo = ((kki * 4 + quad) ^ sw) * 8;
            s16x8 af[4], bf[4];
#pragma unroll
            for (int mi = 0; mi < 4; mi++)
                af[mi] = *(const s16x8*)&As[(rw + mi * 16 + l16) * 64 + xo];
#pragma unroll
            for (int ni = 0; ni < 4; ni++)
                bf[ni] = *(const s16x8*)&Bs[(cw + ni * 16 + l16) * 64 + xo];
#pragma unroll
            for (int mi = 0; mi < 4; mi++)
#pragma unroll
                for (int ni = 0; ni < 4; ni++)
                    acc[mi][ni] = __builtin_amdgcn_mfma_f32_16x16x32_bf16(af[mi], bf[ni], acc[mi][ni], 0, 0, 0);
        }
        __syncthreads();
    }

    float bv[4];
#pragma unroll
    for (int ni = 0; ni < 4; ni++) bv[ni] = bias[n0 + cw + ni * 16 + l16];
#pragma unroll
    for (int mi = 0; mi < 4; mi++) {
        const int rb = m0 + rw + mi * 16 + quad * 4;
        const int b = rb >> 11, s0 = rb & 2047;
#pragma unroll
        for (int ni = 0; ni < 4; ni++) {
            const int col = n0 + cw + ni * 16 + l16;
            if (MODE == 3) {
#pragma unroll
                for (int i = 0; i < 4; i++)
                    ((float*)Y)[(size_t)(rb + i) * 1024 + col] = (acc[mi][ni][i] + bv[ni]) * scale;
            } else {
                const int h = col >> 6, dk = col & 63;
                if (MODE == 1) {
#pragma unroll
                    for (int i = 0; i < 4; i++)
                        ((unsigned short*)Y)[((size_t)(b * H_ + h) * S_ + s0 + i) * DK_ + dk] =
                            f2bf((acc[mi][ni][i] + bv[ni]) * scale);
                } else {
                    u16x4 pk;
#pragma unroll
                    for (int i = 0; i < 4; i++) pk[i] = f2bf((acc[mi][ni][i] + bv[ni]) * scale);
                    *(u16x4*)&((unsigned short*)Y)[((size_t)(b * H_ + h) * DK_ + dk) * S_ + s0] = pk;
                }
            }
        }
    }
}

// ---------------- Flash attention (St layout, barrier-free) ----------------
// Grid (S/128, B*H), block 256 = 4 waves; wave owns 32 q rows (2 blocks of 16).
// K/V fragments loaded DIRECTLY from global ((B,H,S,DK) / (B,H,DK,S) are
// fragment-native layouts); only P round-trips through wave-private LDS strips.
// No __syncthreads anywhere. Mask folded into MFMA acc init (-inf -> exp2 -> +0).
__global__ __launch_bounds__(256) void attn_kernel(const unsigned short* __restrict__ Q,
                                                   const unsigned short* __restrict__ K,
                                                   const unsigned short* __restrict__ Vt,
                                                   const unsigned long long* __restrict__ pm,
                                                   unsigned short* __restrict__ ctx) {
    __shared__ __align__(16) unsigned short Ps[8 * 16 * 64]; // 16 KB, swizzled strips

    const int tid = threadIdx.x;
    const int wave = tid >> 6, lane = tid & 63, quad = lane >> 4, l16 = lane & 15;
    const int bh = blockIdx.y, b = bh >> 4, h = bh & 15;
    const int qbase = blockIdx.x * 128 + wave * 32;
    const int sw = l16 & 7, q4 = quad * 4, qh = quad >> 1;

    // per-lane fragment base pointers
    const unsigned short* Kfrag = K + ((size_t)bh * S_ + l16) * DK_ + quad * 8;   // + (k0+ct*16)*DK_ + kki*32
    const unsigned short* Vfrag = Vt + ((size_t)bh * DK_ + l16) * S_ + quad * 8;  // + ct*16*S_ + k0 + kki*32

    // Q fragments (B-operand): B[n=q=l16][k=d]
    s16x8 qf[2][2];
#pragma unroll
    for (int qb = 0; qb < 2; qb++) {
        const unsigned short* qr = Q + ((size_t)bh * S_ + qbase + qb * 16 + l16) * DK_ + quad * 8;
        qf[qb][0] = *(const s16x8*)qr;
        qf[qb][1] = *(const s16x8*)(qr + 32);
    }
    // inverted mask row pointers (bit=1 -> masked out)
    const unsigned long long* pmq[2];
#pragma unroll
    for (int qb = 0; qb < 2; qb++)
        pmq[qb] = pm + ((size_t)b * S_ + qbase + qb * 16 + l16) * 32;

    s16x8 ones;
#pragma unroll
    for (int j = 0; j < 8; j++) ones[j] = (short)0x3F80; // bf16 1.0

    f32x4 oacc[2][4], lacc[2];
#pragma unroll
    for (int qb = 0; qb < 2; qb++) {
        lacc[qb] = (f32x4){0.f, 0.f, 0.f, 0.f};
#pragma unroll
        for (int ct = 0; ct < 4; ct++) oacc[qb][ct] = (f32x4){0.f, 0.f, 0.f, 0.f};
    }

    for (int kt = 0; kt < S_ / 64; kt++) {
        const int k0 = kt * 64;

        // init sacc from inverted mask: masked -> -inf (exp2 -> +0), else 0
        f32x4 sacc[2][4];
#pragma unroll
        for (int qb = 0; qb < 2; qb++) {
            const uint2 mv = *(const uint2*)&pmq[qb][kt];
            const unsigned mqx = mv.x >> q4, mqy = mv.y >> q4;
#pragma unroll
            for (int ct = 0; ct < 4; ct++) {
                const unsigned mq = (ct & 2) ? mqy : mqx;
#pragma unroll
                for (int i = 0; i < 4; i++) {
                    const int mb = __builtin_amdgcn_sbfe(mq, (ct & 1) * 16 + i, 1); // -1 masked / 0 keep
                    sacc[qb][ct][i] = __int_as_float(mb & (int)0xFF800000); // -inf / +0
                }
            }
        }

        // St = K * Q^T, K fragments straight from global
#pragma unroll
        for (int kki = 0; kki < 2; kki++) {
            s16x8 kf[4];
#pragma unroll
            for (int ct = 0; ct < 4; ct++)
                kf[ct] = *(const s16x8*)(Kfrag + (size_t)(k0 + ct * 16) * DK_ + kki * 32);
#pragma unroll
            for (int qb = 0; qb < 2; qb++)
#pragma unroll
                for (int ct = 0; ct < 4; ct++)
                    sacc[qb][ct] = __builtin_amdgcn_mfma_f32_16x16x32_bf16(kf[ct], qf[qb][kki], sacc[qb][ct], 0, 0, 0);
        }

        // exp2 + perm-pack + swizzled strip write (wave-private)
#pragma unroll
        for (int qb = 0; qb < 2; qb++) {
            unsigned short* pwq = &Ps[(wave * 2 + qb) * 1024];
#pragma unroll
            for (int ct = 0; ct < 4; ct++) {
                unsigned pu[4];
#pragma unroll
                for (int i = 0; i < 4; i++)
                    pu[i] = __float_as_uint(exp2f(sacc[qb][ct][i]));
                const int ch = ((2 * ct + qh) ^ sw) * 8;
#pragma unroll
                for (int t = 0; t < 2; t++) {
                    const unsigned pk = __builtin_amdgcn_perm(pu[2 * t + 1], pu[2 * t], 0x07060302u);
                    *(unsigned*)&pwq[l16 * 64 + ch + ((q4 + 2 * t) & 7)] = pk;
                }
            }
        }

        // O += P*V ; l += P*ones  (V fragments straight from global)
#pragma unroll
        for (int kki = 0; kki < 2; kki++) {
            const int xo = ((kki * 4 + quad) ^ sw) * 8;
            s16x8 vf[4];
#pragma unroll
            for (int ct = 0; ct < 4; ct++)
                vf[ct] = *(const s16x8*)(Vfrag + (size_t)(ct * 16) * S_ + k0 + kki * 32);
#pragma unroll
            for (int qb = 0; qb < 2; qb++) {
                s16x8 pf = *(const s16x8*)&Ps[(wave * 2 + qb) * 1024 + l16 * 64 + xo];
#pragma unroll
                for (int ct = 0; ct < 4; ct++)
                    oacc[qb][ct] = __builtin_amdgcn_mfma_f32_16x16x32_bf16(pf, vf[ct], oacc[qb][ct], 0, 0, 0);
                lacc[qb] = __builtin_amdgcn_mfma_f32_16x16x32_bf16(pf, ones, lacc[qb], 0, 0, 0);
            }
        }
    }

    // epilogue: O rows (q=quad*4+i) align with lacc rows; normalize + write
#pragma unroll
    for (int qb = 0; qb < 2; qb++) {
        f32x4 rl;
#pragma unroll
        for (int i = 0; i < 4; i++) rl[i] = 1.0f / lacc[qb][i];
#pragma unroll
        for (int ct = 0; ct < 4; ct++) {
            const int col = h * DK_ + ct * 16 + l16;
#pragma unroll
            for (int i = 0; i < 4; i++) {
                const int sg = qbase + qb * 16 + quad * 4 + i;
                ctx[((size_t)(b * S_ + sg)) * D_ + col] = f2bf(oacc[qb][ct][i] * rl[i]);
            }
        }
    }
}

// ---------------- launch ----------------
extern "C" void kernel_launch(void* const* d_in, const int* in_sizes, int n_in,
                              void* d_out, int out_size, void* d_ws, size_t ws_size,
                              hipStream_t stream) {
    const float* query = (const float*)d_in[0];
    const float* key   = (const float*)d_in[1];
    const float* value = (const float*)d_in[2];
    const int*   mask  = (const int*)d_in[3];
    const float* w_q = (const float*)d_in[4];
    const float* b_q = (const float*)d_in[5];
    const float* w_k = (const float*)d_in[6];
    const float* b_k = (const float*)d_in[7];
    const float* w_v = (const float*)d_in[8];
    const float* b_v = (const float*)d_in[9];
    const float* w_o = (const float*)d_in[10];
    const float* b_o = (const float*)d_in[11];

    char* ws = (char*)d_ws;
    const size_t XSZ = (size_t)M_ * D_ * 2;  // 16 MB
    const size_t WSZ = (size_t)D_ * D_ * 2;  // 2 MB
    unsigned short* Xq  = (unsigned short*)(ws);
    unsigned short* Xk  = (unsigned short*)(ws + XSZ);
    unsigned short* Xv  = (unsigned short*)(ws + 2 * XSZ);
    unsigned short* Wq  = (unsigned short*)(ws + 3 * XSZ);
    unsigned short* Wk  = (unsigned short*)(ws + 3 * XSZ + WSZ);
    unsigned short* Wv  = (unsigned short*)(ws + 3 * XSZ + 2 * WSZ);
    unsigned short* Wo  = (unsigned short*)(ws + 3 * XSZ + 3 * WSZ);
    unsigned short* Qb  = (unsigned short*)(ws + 3 * XSZ + 4 * WSZ);
    unsigned short* Kb  = (unsigned short*)(ws + 4 * XSZ + 4 * WSZ);
    unsigned short* Vtb = (unsigned short*)(ws + 5 * XSZ + 4 * WSZ);
    unsigned short* ctx = (unsigned short*)(ws + 6 * XSZ + 4 * WSZ);
    unsigned long long* pm = (unsigned long long*)(ws); // overlaps Xq (dead after Q GEMM)

    const int nTok = M_ * D_;
    const int nW = D_ * D_;
    hipLaunchKernelGGL(cvt_bf16x3, dim3(nTok / 2048, 3), dim3(256), 0, stream,
                       query, key, value, Xq, Xk, Xv, nTok);
    hipLaunchKernelGGL(cvt_bf16x4, dim3(nW / 2048, 4), dim3(256), 0, stream,
                       w_q, w_k, w_v, w_o, Wq, Wk, Wv, Wo, nW);

    const float QSCALE = 0.125f * 1.44269504f; // fold /sqrt(DK) and log2(e) into Q
    dim3 ggrid(M_ / 128, D_ / 128); // 64 x 8
    hipLaunchKernelGGL(HIP_KERNEL_NAME(gemm_bt<1>), ggrid, dim3(256), 0, stream, Xq, Wq, b_q, QSCALE, (void*)Qb);
    hipLaunchKernelGGL(HIP_KERNEL_NAME(gemm_bt<1>), ggrid, dim3(256), 0, stream, Xk, Wk, b_k, 1.0f, (void*)Kb);
    hipLaunchKernelGGL(HIP_KERNEL_NAME(gemm_bt<2>), ggrid, dim3(256), 0, stream, Xv, Wv, b_v, 1.0f, (void*)Vtb);

    hipLaunchKernelGGL(pack_mask, dim3((B_ * S_ * S_) / 256), dim3(256), 0, stream, mask, pm);

    hipLaunchKernelGGL(attn_kernel, dim3(S_ / 128, B_ * H_), dim3(256), 0, stream,
                       Qb, Kb, Vtb, pm, ctx);

    hipLaunchKernelGGL(HIP_KERNEL_NAME(gemm_bt<3>), ggrid, dim3(256), 0, stream, ctx, Wo, b_o, 1.0f, d_out);
}